// Round 3
// baseline (145.307 us; speedup 1.0000x reference)
//
#include <hip/hip_runtime.h>
#include <hip/hip_bf16.h>

#define NN 8192
#define DD 128
#define BM 16

typedef __attribute__((ext_vector_type(4))) float f32x4;
typedef __attribute__((ext_vector_type(8))) short bf16x8;

__device__ __forceinline__ unsigned short f2bf(float x) {
    unsigned u = __float_as_uint(x);
    u += 0x7fffu + ((u >> 16) & 1u);   // round-to-nearest-even
    return (unsigned short)(u >> 16);
}

// ---------------------------------------------------------------------------
// Kernel A: hT[n][j] = bf16( B[n] + sum_k z[j][k] * W[k][n] ), plain layout.
// ---------------------------------------------------------------------------
__global__ void __launch_bounds__(256) h_transform(
    const float* __restrict__ z, const float* __restrict__ W,
    const float* __restrict__ Bv, unsigned short* __restrict__ hT) {
    __shared__ float zs[BM * DD];      // 16 x 128 f32 (8 KB)
    __shared__ float wt[DD * 132];     // W transposed [n][k], pad 132
    const int t = threadIdx.x;
    const int j0 = blockIdx.x * BM;

    {   // stage z rows
        const f32x4* zsrc = (const f32x4*)(z + (size_t)j0 * DD);
        f32x4* zdst = (f32x4*)zs;
        zdst[t] = zsrc[t];
        zdst[t + 256] = zsrc[t + 256];
    }
    // stage W transposed
    for (int q = t; q < DD * 32; q += 256) {
        int k = q >> 5;
        int n0 = (q & 31) << 2;
        f32x4 wv = *(const f32x4*)(W + k * DD + n0);
        wt[(n0 + 0) * 132 + k] = wv[0];
        wt[(n0 + 1) * 132 + k] = wv[1];
        wt[(n0 + 2) * 132 + k] = wv[2];
        wt[(n0 + 3) * 132 + k] = wv[3];
    }
    __syncthreads();

    const int n = t >> 1;          // 0..127
    const int ja = (t & 1) << 3;   // 0 or 8
    float acc[8];
    float bn = Bv[n];
#pragma unroll
    for (int e = 0; e < 8; e++) acc[e] = bn;

#pragma unroll 8
    for (int k4 = 0; k4 < 32; ++k4) {
        f32x4 wv = *(const f32x4*)&wt[n * 132 + (k4 << 2)];
#pragma unroll
        for (int e = 0; e < 8; e++) {
            f32x4 zv = *(const f32x4*)&zs[(ja + e) * DD + (k4 << 2)];
            acc[e] += zv[0] * wv[0] + zv[1] * wv[1] + zv[2] * wv[2] + zv[3] * wv[3];
        }
    }

    const int j = j0 + ja;                 // 8-aligned
    unsigned short* dst = hT + (size_t)n * NN + j;
    uint4 uv;
    uv.x = (unsigned)f2bf(acc[0]) | ((unsigned)f2bf(acc[1]) << 16);
    uv.y = (unsigned)f2bf(acc[2]) | ((unsigned)f2bf(acc[3]) << 16);
    uv.z = (unsigned)f2bf(acc[4]) | ((unsigned)f2bf(acc[5]) << 16);
    uv.w = (unsigned)f2bf(acc[6]) | ((unsigned)f2bf(acc[7]) << 16);
    *(uint4*)dst = uv;
}

// ---------------------------------------------------------------------------
// Kernel B: barrier-free fused S-compute + S@h GEMM.
// One wave per block; 32 output rows x 128 cols; K-range [kbeg, kbeg+klen).
// dist loaded NON-TEMPORAL (read-once 256 MB stream must not evict the
// L2-resident 2 MB hT, whose 512 MB of re-reads would otherwise hit HBM).
// A-frag (S) computed in-register from dist in MFMA lane layout; B-frag (hT)
// register-direct from L2. Register double-buffer, zero LDS, zero barriers.
// ---------------------------------------------------------------------------
__device__ __forceinline__ bf16x8 sfrag(f32x4 a, f32x4 b, int jbase, int diag,
                                        float inv_mu, float ninv2s2) {
    float v0[4] = {a[0], a[1], a[2], a[3]};
    float v1[4] = {b[0], b[1], b[2], b[3]};
    unsigned short h[8];
#pragma unroll
    for (int e = 0; e < 4; ++e) {
        float d = v0[e];
        float q = __builtin_amdgcn_rcpf(d) - inv_mu;
        float s = __expf(q * q * ninv2s2);
        bool keep = (d < 0.5f) & ((jbase + e) != diag);
        h[e] = f2bf(keep ? s : 0.0f);
    }
#pragma unroll
    for (int e = 0; e < 4; ++e) {
        float d = v1[e];
        float q = __builtin_amdgcn_rcpf(d) - inv_mu;
        float s = __expf(q * q * ninv2s2);
        bool keep = (d < 0.5f) & ((jbase + 4 + e) != diag);
        h[4 + e] = f2bf(keep ? s : 0.0f);
    }
    uint4 u;
    u.x = (unsigned)h[0] | ((unsigned)h[1] << 16);
    u.y = (unsigned)h[2] | ((unsigned)h[3] << 16);
    u.z = (unsigned)h[4] | ((unsigned)h[5] << 16);
    u.w = (unsigned)h[6] | ((unsigned)h[7] << 16);
    return __builtin_bit_cast(bf16x8, u);
}

__global__ void __launch_bounds__(64) fused_interact(
    const float* __restrict__ dist, const unsigned short* __restrict__ hT,
    const float* __restrict__ mu, const float* __restrict__ sigma,
    float* __restrict__ outp, float* __restrict__ part, int ksplit) {
    const int l = threadIdx.x;
    const int rt = blockIdx.x / ksplit;
    const int ks = blockIdx.x - rt * ksplit;
    const int klen = NN / ksplit;
    const int kbeg = ks * klen;

    const int row = l & 15;
    const int kc8 = (l >> 4) << 3;
    const int r0 = rt * 32;

    const float inv_mu = 1.0f / mu[0];
    const float sg = sigma[0];
    const float ninv2s2 = -1.0f / (2.0f * sg * sg);

    const float* dp0 = dist + (size_t)(r0 + row) * NN + kc8;
    const float* dp1 = dp0 + (size_t)16 * NN;
    const unsigned short* hp = hT + (size_t)row * NN + kc8;
    const int diag0 = r0 + row;
    const int diag1 = diag0 + 16;

    f32x4 acc[2][8];
#pragma unroll
    for (int m = 0; m < 2; ++m)
#pragma unroll
        for (int f = 0; f < 8; ++f) acc[m][f] = (f32x4){0.f, 0.f, 0.f, 0.f};

    f32x4 dA0a, dA0b, dA1a, dA1b, dB0a, dB0b, dB1a, dB1b;
    uint4 hA[8], hB[8];

#define LOADD(Da, Db, Dc, Dd, H, K)                                          \
    do {                                                                     \
        Da = __builtin_nontemporal_load((const f32x4*)(dp0 + (K)));          \
        Db = __builtin_nontemporal_load((const f32x4*)(dp0 + (K) + 4));      \
        Dc = __builtin_nontemporal_load((const f32x4*)(dp1 + (K)));          \
        Dd = __builtin_nontemporal_load((const f32x4*)(dp1 + (K) + 4));      \
        _Pragma("unroll") for (int f = 0; f < 8; ++f)                        \
            H[f] = *(const uint4*)(hp + (size_t)f * 16 * NN + (K));          \
    } while (0)

#define COMPUTE(Da, Db, Dc, Dd, H, K)                                        \
    do {                                                                     \
        bf16x8 a0 = sfrag(Da, Db, (K) + kc8, diag0, inv_mu, ninv2s2);        \
        bf16x8 a1 = sfrag(Dc, Dd, (K) + kc8, diag1, inv_mu, ninv2s2);        \
        _Pragma("unroll") for (int f = 0; f < 8; ++f) {                      \
            bf16x8 bb = __builtin_bit_cast(bf16x8, H[f]);                    \
            acc[0][f] = __builtin_amdgcn_mfma_f32_16x16x32_bf16(             \
                a0, bb, acc[0][f], 0, 0, 0);                                 \
            acc[1][f] = __builtin_amdgcn_mfma_f32_16x16x32_bf16(             \
                a1, bb, acc[1][f], 0, 0, 0);                                 \
        }                                                                    \
    } while (0)

    int k = kbeg;
    LOADD(dA0a, dA0b, dA1a, dA1b, hA, k);
    LOADD(dB0a, dB0b, dB1a, dB1b, hB, k + 32);
    const int nt = klen >> 5;   // iterations of K=32; always even here
    for (int it = 0; it < nt; it += 2) {
        COMPUTE(dA0a, dA0b, dA1a, dA1b, hA, k);
        if (it + 2 < nt) LOADD(dA0a, dA0b, dA1a, dA1b, hA, k + 64);
        COMPUTE(dB0a, dB0b, dB1a, dB1b, hB, k + 32);
        if (it + 3 < nt) LOADD(dB0a, dB0b, dB1a, dB1b, hB, k + 96);
        k += 64;
    }

    float* po = (ksplit == 1) ? outp : (part + (size_t)ks * (NN * DD));
    const int orow = r0 + ((l >> 4) << 2);
    const int ocol = l & 15;
#pragma unroll
    for (int m = 0; m < 2; ++m)
#pragma unroll
        for (int f = 0; f < 8; ++f)
#pragma unroll
            for (int rr = 0; rr < 4; ++rr)
                po[(size_t)(orow + m * 16 + rr) * DD + f * 16 + ocol] =
                    acc[m][f][rr];
}

// ---------------------------------------------------------------------------
// Kernel C: sum K-split partials into out.
// ---------------------------------------------------------------------------
__global__ void __launch_bounds__(256) reduce_part(
    const float* __restrict__ part, float* __restrict__ outp, int ksplit) {
    const size_t idx = ((size_t)blockIdx.x * 256 + threadIdx.x) << 2;
    f32x4 s = *(const f32x4*)(part + idx);
    for (int ksp = 1; ksp < ksplit; ++ksp)
        s += *(const f32x4*)(part + (size_t)ksp * (NN * DD) + idx);
    *(f32x4*)(outp + idx) = s;
}

extern "C" void kernel_launch(void* const* d_in, const int* in_sizes, int n_in,
                              void* d_out, int out_size, void* d_ws, size_t ws_size,
                              hipStream_t stream) {
    const float* z = (const float*)d_in[0];
    const float* dist = (const float*)d_in[1];
    const float* W = (const float*)d_in[2];
    const float* Bv = (const float*)d_in[3];
    const float* mu = (const float*)d_in[4];
    const float* sigma = (const float*)d_in[5];
    float* out = (float*)d_out;

    unsigned short* hT = (unsigned short*)d_ws;           // 2 MB
    const size_t hT_bytes = (size_t)DD * NN * 2;
    const size_t part_bytes = (size_t)NN * DD * 4;        // 4 MB per split
    float* part = (float*)((char*)d_ws + hT_bytes);

    int ksplit = 1;
    if (ws_size >= hT_bytes + 4 * part_bytes) ksplit = 4;
    else if (ws_size >= hT_bytes + 2 * part_bytes) ksplit = 2;

    h_transform<<<NN / BM, 256, 0, stream>>>(z, W, Bv, hT);
    fused_interact<<<(NN / 32) * ksplit, 64, 0, stream>>>(dist, hT, mu, sigma,
                                                          out, part, ksplit);
    if (ksplit > 1)
        reduce_part<<<(NN * DD) / 1024, 256, 0, stream>>>(part, out, ksplit);
}

// Round 4
// 108.599 us; speedup vs baseline: 1.3380x; 1.3380x over previous
//
#include <hip/hip_runtime.h>
#include <hip/hip_bf16.h>

#define NN 8192
#define DD 128
#define BM 16
#define JS 8          // j-slices (K-split)
#define RPB 256       // output rows per block
#define JSLICE 1024   // j columns per block
#define JCHUNK 512    // j columns per LDS stage
#define LSTR 1040     // LDS bytes per n-row: 512*2 + 16 pad (bank-conflict-free)

typedef __attribute__((ext_vector_type(4))) float f32x4;
typedef __attribute__((ext_vector_type(8))) short bf16x8;

__device__ __forceinline__ unsigned short f2bf(float x) {
    unsigned u = __float_as_uint(x);
    u += 0x7fffu + ((u >> 16) & 1u);   // round-to-nearest-even
    return (unsigned short)(u >> 16);
}

// ---------------------------------------------------------------------------
// Kernel A: hT[n][j] = bf16( B[n] + sum_k z[j][k] * W[k][n] ), plain layout.
// ---------------------------------------------------------------------------
__global__ void __launch_bounds__(256) h_transform(
    const float* __restrict__ z, const float* __restrict__ W,
    const float* __restrict__ Bv, unsigned short* __restrict__ hT) {
    __shared__ float zs[BM * DD];
    __shared__ float wt[DD * 132];
    const int t = threadIdx.x;
    const int j0 = blockIdx.x * BM;

    {
        const f32x4* zsrc = (const f32x4*)(z + (size_t)j0 * DD);
        f32x4* zdst = (f32x4*)zs;
        zdst[t] = zsrc[t];
        zdst[t + 256] = zsrc[t + 256];
    }
    for (int q = t; q < DD * 32; q += 256) {
        int k = q >> 5;
        int n0 = (q & 31) << 2;
        f32x4 wv = *(const f32x4*)(W + k * DD + n0);
        wt[(n0 + 0) * 132 + k] = wv[0];
        wt[(n0 + 1) * 132 + k] = wv[1];
        wt[(n0 + 2) * 132 + k] = wv[2];
        wt[(n0 + 3) * 132 + k] = wv[3];
    }
    __syncthreads();

    const int n = t >> 1;
    const int ja = (t & 1) << 3;
    float acc[8];
    float bn = Bv[n];
#pragma unroll
    for (int e = 0; e < 8; e++) acc[e] = bn;

#pragma unroll 8
    for (int k4 = 0; k4 < 32; ++k4) {
        f32x4 wv = *(const f32x4*)&wt[n * 132 + (k4 << 2)];
#pragma unroll
        for (int e = 0; e < 8; e++) {
            f32x4 zv = *(const f32x4*)&zs[(ja + e) * DD + (k4 << 2)];
            acc[e] += zv[0] * wv[0] + zv[1] * wv[1] + zv[2] * wv[2] + zv[3] * wv[3];
        }
    }

    const int j = j0 + ja;
    unsigned short* dst = hT + (size_t)n * NN + j;
    uint4 uv;
    uv.x = (unsigned)f2bf(acc[0]) | ((unsigned)f2bf(acc[1]) << 16);
    uv.y = (unsigned)f2bf(acc[2]) | ((unsigned)f2bf(acc[3]) << 16);
    uv.z = (unsigned)f2bf(acc[4]) | ((unsigned)f2bf(acc[5]) << 16);
    uv.w = (unsigned)f2bf(acc[6]) | ((unsigned)f2bf(acc[7]) << 16);
    *(uint4*)dst = uv;
}

// ---------------------------------------------------------------------------
// Kernel B: fused S + S@h with LDS-persistent hT slice.
// Grid: 32 row-blocks x 8 j-slices. Block: 512 thr (8 waves x 32 rows),
// j-slice 1024 staged as 2 x [128 n][512 j] LDS tiles (130 KB, padded rows).
// Inner loop identical to the proven barrier-free r2 pipeline, with hT
// B-frags read from LDS instead of HBM. 4 barriers per block total.
// ---------------------------------------------------------------------------
__device__ __forceinline__ bf16x8 sfrag(f32x4 a, f32x4 b, int jbase, int diag,
                                        float inv_mu, float ninv2s2) {
    float v0[4] = {a[0], a[1], a[2], a[3]};
    float v1[4] = {b[0], b[1], b[2], b[3]};
    unsigned short h[8];
#pragma unroll
    for (int e = 0; e < 4; ++e) {
        float d = v0[e];
        float q = __builtin_amdgcn_rcpf(d) - inv_mu;
        float s = __expf(q * q * ninv2s2);
        bool keep = (d < 0.5f) & ((jbase + e) != diag);
        h[e] = f2bf(keep ? s : 0.0f);
    }
#pragma unroll
    for (int e = 0; e < 4; ++e) {
        float d = v1[e];
        float q = __builtin_amdgcn_rcpf(d) - inv_mu;
        float s = __expf(q * q * ninv2s2);
        bool keep = (d < 0.5f) & ((jbase + 4 + e) != diag);
        h[4 + e] = f2bf(keep ? s : 0.0f);
    }
    uint4 u;
    u.x = (unsigned)h[0] | ((unsigned)h[1] << 16);
    u.y = (unsigned)h[2] | ((unsigned)h[3] << 16);
    u.z = (unsigned)h[4] | ((unsigned)h[5] << 16);
    u.w = (unsigned)h[6] | ((unsigned)h[7] << 16);
    return __builtin_bit_cast(bf16x8, u);
}

__global__ void __launch_bounds__(512, 2) fused_interact(
    const float* __restrict__ dist, const unsigned short* __restrict__ hT,
    const float* __restrict__ mu, const float* __restrict__ sigma,
    float* __restrict__ part) {
    __shared__ uint4 hs4[DD * (LSTR / 16)];     // 128 rows x 1040 B = 130 KB
    char* hs = (char*)hs4;

    const int t = threadIdx.x;
    const int w = t >> 6;
    const int l = t & 63;
    const int rb = blockIdx.x >> 3;
    const int js = blockIdx.x & 7;            // j-slice; bid%8 ~ XCD affinity
    const int r0 = rb * RPB + w * 32;
    const int row = l & 15;
    const int kc8 = (l >> 4) << 3;            // element offset within K-group
    const int q16 = (l >> 4) << 4;            // byte offset within LDS row

    const float inv_mu = 1.0f / mu[0];
    const float sg = sigma[0];
    const float ninv2s2 = -1.0f / (2.0f * sg * sg);

    const float* dp0 = dist + (size_t)(r0 + row) * NN + kc8;
    const float* dp1 = dp0 + (size_t)16 * NN;
    const int diag0 = r0 + row;
    const int diag1 = diag0 + 16;
    const char* hbase = hs + row * LSTR + q16;  // + f*16*LSTR + 2*kloc

    f32x4 acc[2][8];
#pragma unroll
    for (int m = 0; m < 2; ++m)
#pragma unroll
        for (int f = 0; f < 8; ++f) acc[m][f] = (f32x4){0.f, 0.f, 0.f, 0.f};

    f32x4 dA0a, dA0b, dA1a, dA1b, dB0a, dB0b, dB1a, dB1b;

#define LOADD(Da, Db, Dc, Dd, K)                                             \
    do {                                                                     \
        Da = *(const f32x4*)(dp0 + (K));                                     \
        Db = *(const f32x4*)(dp0 + (K) + 4);                                 \
        Dc = *(const f32x4*)(dp1 + (K));                                     \
        Dd = *(const f32x4*)(dp1 + (K) + 4);                                 \
    } while (0)

#define COMPUTE(Da, Db, Dc, Dd, K, LK)                                       \
    do {                                                                     \
        bf16x8 a0 = sfrag(Da, Db, (K) + kc8, diag0, inv_mu, ninv2s2);        \
        bf16x8 a1 = sfrag(Dc, Dd, (K) + kc8, diag1, inv_mu, ninv2s2);        \
        _Pragma("unroll") for (int f = 0; f < 8; ++f) {                      \
            bf16x8 bb = *(const bf16x8*)(hbase + f * (16 * LSTR) + (LK));    \
            acc[0][f] = __builtin_amdgcn_mfma_f32_16x16x32_bf16(             \
                a0, bb, acc[0][f], 0, 0, 0);                                 \
            acc[1][f] = __builtin_amdgcn_mfma_f32_16x16x32_bf16(             \
                a1, bb, acc[1][f], 0, 0, 0);                                 \
        }                                                                    \
    } while (0)

#pragma unroll 1
    for (int chunk = 0; chunk < 2; ++chunk) {
        const int jc = js * JSLICE + chunk * JCHUNK;
        __syncthreads();   // all waves done reading previous tile
        {
            uint4 tmp[16];
#pragma unroll
            for (int i = 0; i < 16; ++i) {
                int c = i * 512 + t;
                int n = c >> 6;
                int cb = c & 63;
                tmp[i] = *(const uint4*)(hT + (size_t)n * NN + jc + cb * 8);
            }
#pragma unroll
            for (int i = 0; i < 16; ++i) {
                int c = i * 512 + t;
                int n = c >> 6;
                int cb = c & 63;
                *(uint4*)(hs + n * LSTR + cb * 16) = tmp[i];
            }
        }
        __syncthreads();   // tile ready

        LOADD(dA0a, dA0b, dA1a, dA1b, jc);
        LOADD(dB0a, dB0b, dB1a, dB1b, jc + 32);
#pragma unroll 1
        for (int it = 0; it < 16; it += 2) {
            const int kg = jc + (it << 5);
            const int lk = it << 6;          // chunk-local byte offset
            COMPUTE(dA0a, dA0b, dA1a, dA1b, kg, lk);
            if (it + 2 < 16) LOADD(dA0a, dA0b, dA1a, dA1b, kg + 64);
            COMPUTE(dB0a, dB0b, dB1a, dB1b, kg + 32, lk + 64);
            if (it + 3 < 16) LOADD(dB0a, dB0b, dB1a, dB1b, kg + 96);
        }
    }

    float* po = part + (size_t)js * (NN * DD);
    const int orow = r0 + ((l >> 4) << 2);
    const int ocol = l & 15;
#pragma unroll
    for (int m = 0; m < 2; ++m)
#pragma unroll
        for (int f = 0; f < 8; ++f)
#pragma unroll
            for (int rr = 0; rr < 4; ++rr)
                po[(size_t)(orow + m * 16 + rr) * DD + f * 16 + ocol] =
                    acc[m][f][rr];
#undef LOADD
#undef COMPUTE
}

// ---------------------------------------------------------------------------
// Kernel C: sum the 8 K-split partials into out.
// ---------------------------------------------------------------------------
__global__ void __launch_bounds__(256) reduce_part(
    const float* __restrict__ part, float* __restrict__ outp) {
    const size_t idx = ((size_t)blockIdx.x * 256 + threadIdx.x) << 2;
    f32x4 s = *(const f32x4*)(part + idx);
#pragma unroll
    for (int ksp = 1; ksp < JS; ++ksp)
        s += *(const f32x4*)(part + (size_t)ksp * (NN * DD) + idx);
    *(f32x4*)(outp + idx) = s;
}

extern "C" void kernel_launch(void* const* d_in, const int* in_sizes, int n_in,
                              void* d_out, int out_size, void* d_ws, size_t ws_size,
                              hipStream_t stream) {
    const float* z = (const float*)d_in[0];
    const float* dist = (const float*)d_in[1];
    const float* W = (const float*)d_in[2];
    const float* Bv = (const float*)d_in[3];
    const float* mu = (const float*)d_in[4];
    const float* sigma = (const float*)d_in[5];
    float* out = (float*)d_out;

    unsigned short* hT = (unsigned short*)d_ws;                 // 2 MB
    const size_t hT_bytes = (size_t)DD * NN * 2;
    float* part = (float*)((char*)d_ws + hT_bytes);             // 8 x 4 MB

    h_transform<<<NN / BM, 256, 0, stream>>>(z, W, Bv, hT);
    fused_interact<<<(NN / RPB) * JS, 512, 0, stream>>>(dist, hT, mu, sigma,
                                                        part);
    reduce_part<<<(NN * DD) / 1024, 256, 0, stream>>>(part, out);
}